// Round 6
// baseline (308.301 us; speedup 1.0000x reference)
//
#include <hip/hip_runtime.h>
#include <math.h>

#define BB 128
#define SS 200
#define MM 50
#define DKK 64
#define DVV 128
#define FF 64
#define NROW (BB*SS)   // 25600

// w padded layout: direct m index, 64 floats/row, m in [0,50) valid, rest zero
#define WROW 64

// workspace layout (floats)
#define W_OFF   0L
#define E_OFF   (W_OFF + (long)NROW*WROW)
#define A_OFF   (E_OFF + (long)NROW*DVV)
#define R_OFF   (A_OFF + (long)NROW*DVV)
#define ACC_OFF (R_OFF + (long)NROW*DVV)

// ---------------- Kernel 1: w = softmax(q_e @ mem_key^T) ----------------
// 200 blocks x 128 threads (1 item/thread); mem_key staged in LDS, b128 broadcasts.
__global__ __launch_bounds__(128) void k_scores(const int* __restrict__ q_data,
                                                const float* __restrict__ q_embed_w,
                                                const float* __restrict__ mem_key,
                                                float* __restrict__ w_out,
                                                float* __restrict__ acc) {
    __shared__ float4 mk[MM * 16];   // 12.8 KB
    int tid = threadIdx.x;
    const float4* mkg = (const float4*)mem_key;
    for (int i = tid; i < MM * 16; i += 128) mk[i] = mkg[i];
    if (blockIdx.x == 0 && tid == 0) { acc[0] = 0.f; acc[1] = 0.f; }
    __syncthreads();

    int item = blockIdx.x * 128 + tid;
    int qidx = q_data[item];
    const float4* qg = (const float4*)(q_embed_w + (long)qidx * DKK);
    float4 q[16];
#pragma unroll
    for (int i = 0; i < 16; i++) q[i] = qg[i];

    float s[MM];
    float mx = -1e30f;
#pragma unroll 2
    for (int m = 0; m < MM; m++) {
        float a = 0.f;
#pragma unroll
        for (int k4 = 0; k4 < 16; k4++) {
            float4 mkv = mk[m * 16 + k4];
            float4 qv = q[k4];
            a = fmaf(qv.x, mkv.x, a);
            a = fmaf(qv.y, mkv.y, a);
            a = fmaf(qv.z, mkv.z, a);
            a = fmaf(qv.w, mkv.w, a);
        }
        s[m] = a;
        mx = fmaxf(mx, a);
    }
    float sum = 0.f;
#pragma unroll
    for (int m = 0; m < MM; m++) { s[m] = expf(s[m] - mx); sum += s[m]; }
    float inv = 1.f / sum;

    float* wo = w_out + (long)item * WROW;
#pragma unroll
    for (int m = 0; m < MM; m++) wo[m] = s[m] * inv;
#pragma unroll
    for (int m = MM; m < WROW; m++) wo[m] = 0.f;
}

// ---------------- Kernel 2: e/a GEMM — 64 rows x 128 v per block, 8 rows/thread ----------------
// vq=tid&31 owns v in {vq,vq+32,vq+64,vq+96}; rh=tid>>5 owns 8 rows.
// K chunked by 32 (4 passes); per kk-chunk: 16 b128 serve 256 FMA. 46 KB LDS -> 3 blk/CU.
__global__ __launch_bounds__(256) void k_ea(const int* __restrict__ qa_data,
                                            const float* __restrict__ qa_embed_w,
                                            const float* __restrict__ erase_w,
                                            const float* __restrict__ erase_b,
                                            const float* __restrict__ add_w,
                                            const float* __restrict__ add_b,
                                            float* __restrict__ E,
                                            float* __restrict__ A) {
    __shared__ float Wel[128 * 36];   // 18.4 KB
    __shared__ float Wal[128 * 36];   // 18.4 KB
    __shared__ float xl[64 * 36];     //  9.2 KB
    int tid = threadIdx.x;
    int r0 = blockIdx.x * 64;
    int vq = tid & 31;
    int rh = tid >> 5;   // 0..7

    float acc_e[4][8], acc_a[4][8];
#pragma unroll
    for (int i = 0; i < 4; i++)
#pragma unroll
        for (int j = 0; j < 8; j++) { acc_e[i][j] = 0.f; acc_a[i][j] = 0.f; }

    for (int kc = 0; kc < 4; kc++) {
        __syncthreads();
        for (int i = tid; i < 2048; i += 256) {          // 2 mats x 128 v x 8 float4
            int mat = i >> 10;
            int r = (i >> 3) & 127, p = i & 7;
            const float* src = (mat ? add_w : erase_w) + r * 128 + kc * 32 + p * 4;
            float* dst = (mat ? Wal : Wel) + r * 36 + p * 4;
            *(float4*)dst = *(const float4*)src;
        }
        for (int i = tid; i < 512; i += 256) {           // 64 rows x 8 float4
            int r = i >> 3, p = i & 7;
            int idx = qa_data[r0 + r];
            *(float4*)(xl + r * 36 + p * 4) =
                *(const float4*)(qa_embed_w + (long)idx * DVV + kc * 32 + p * 4);
        }
        __syncthreads();
#pragma unroll
        for (int kk = 0; kk < 32; kk += 4) {
            float4 we[4], wa[4], x4[8];
#pragma unroll
            for (int i = 0; i < 4; i++) {
                we[i] = *(const float4*)(Wel + (vq + 32 * i) * 36 + kk);
                wa[i] = *(const float4*)(Wal + (vq + 32 * i) * 36 + kk);
            }
#pragma unroll
            for (int j = 0; j < 8; j++)
                x4[j] = *(const float4*)(xl + (rh * 8 + j) * 36 + kk);
#pragma unroll
            for (int i = 0; i < 4; i++)
#pragma unroll
                for (int j = 0; j < 8; j++) {
                    acc_e[i][j] = fmaf(x4[j].x, we[i].x, acc_e[i][j]);
                    acc_e[i][j] = fmaf(x4[j].y, we[i].y, acc_e[i][j]);
                    acc_e[i][j] = fmaf(x4[j].z, we[i].z, acc_e[i][j]);
                    acc_e[i][j] = fmaf(x4[j].w, we[i].w, acc_e[i][j]);
                    acc_a[i][j] = fmaf(x4[j].x, wa[i].x, acc_a[i][j]);
                    acc_a[i][j] = fmaf(x4[j].y, wa[i].y, acc_a[i][j]);
                    acc_a[i][j] = fmaf(x4[j].z, wa[i].z, acc_a[i][j]);
                    acc_a[i][j] = fmaf(x4[j].w, wa[i].w, acc_a[i][j]);
                }
        }
    }
#pragma unroll
    for (int i = 0; i < 4; i++) {
        int v = vq + 32 * i;
        float eb = erase_b[v], ab = add_b[v];
#pragma unroll
        for (int j = 0; j < 8; j++) {
            int row = r0 + rh * 8 + j;
            E[(long)row * DVV + v] = 1.f / (1.f + expf(-(acc_e[i][j] + eb)));
            A[(long)row * DVV + v] = tanhf(acc_a[i][j] + ab);
        }
    }
}

// ---------------- Kernel 3: scan — m split 16-way, depth-4 pipeline ----------------
// 512 blocks (b, v-quarter) x 512 threads: v = vh*32 + (tid>>4), mh = tid&15.
// 4 m-slots/thread (pads have w=0 -> exact no-op). 16 waves/CU = 4/SIMD.
// Reduction = 4 shfl_xor within 16-lane groups. No LDS, no barriers.
__global__ __launch_bounds__(512) void k_scan(const float* __restrict__ w_pad,
                                              const float* __restrict__ E,
                                              const float* __restrict__ A,
                                              const float* __restrict__ init_mv,
                                              float* __restrict__ R) {
    int b  = blockIdx.x >> 2;
    int vh = blockIdx.x & 3;
    int tid = threadIdx.x;
    int v = vh * 32 + (tid >> 4);
    int mh = tid & 15;
    int m0 = mh * 4;

    float Mv[4];
#pragma unroll
    for (int j = 0; j < 4; j++) {
        int m = m0 + j;
        Mv[j] = (m < MM) ? init_mv[m * DVV + v] : 0.f;
    }

    const float* wbase = w_pad + (long)b * SS * WROW + m0;
    const float* Eb = E + (long)b * SS * DVV + v;
    const float* Ab = A + (long)b * SS * DVV + v;
    float* Rb = R + (long)b * SS * DVV + v;

    float4 w[4];
    float ee[4], aa[4];
#pragma unroll
    for (int d = 0; d < 4; d++) {
        w[d] = *(const float4*)(wbase + d * WROW);
        ee[d] = Eb[d * DVV];
        aa[d] = Ab[d * DVV];
    }

    for (int t = 0; t < SS; t += 4) {
#pragma unroll
        for (int d = 0; d < 4; d++) {
            int tc = t + d;
            float4 wv = w[d];
            float e = ee[d], a = aa[d];

            float rd;
            float tmp0 = fmaf(-e, Mv[0], a);
            float tmp1 = fmaf(-e, Mv[1], a);
            float tmp2 = fmaf(-e, Mv[2], a);
            float tmp3 = fmaf(-e, Mv[3], a);
            rd = wv.x * Mv[0];
            rd = fmaf(wv.y, Mv[1], rd);
            rd = fmaf(wv.z, Mv[2], rd);
            rd = fmaf(wv.w, Mv[3], rd);
            Mv[0] = fmaf(wv.x, tmp0, Mv[0]);
            Mv[1] = fmaf(wv.y, tmp1, Mv[1]);
            Mv[2] = fmaf(wv.z, tmp2, Mv[2]);
            Mv[3] = fmaf(wv.w, tmp3, Mv[3]);

            rd += __shfl_xor(rd, 1, 64);
            rd += __shfl_xor(rd, 2, 64);
            rd += __shfl_xor(rd, 4, 64);
            rd += __shfl_xor(rd, 8, 64);
            if (mh == 0) Rb[tc * DVV] = rd;

            int tp = tc + 4; if (tp > SS - 1) tp = SS - 1;
            w[d] = *(const float4*)(wbase + tp * WROW);
            ee[d] = Eb[tp * DVV];
            aa[d] = Ab[tp * DVV];
        }
    }
}

// ---------------- Kernel 4: FC head + BCE — 64 rows x 64 f per block ----------------
// thread: fq=tid&15 owns f in {fq,fq+16,fq+32,fq+48}; rh=tid>>4 owns 4 rows.
// W (stride 196) staged once; x = [R || q_e] (stride 100) chunked K=96. 76 KB LDS.
__global__ __launch_bounds__(256) void k_fc(const float* __restrict__ Rr,
                                            const int* __restrict__ q_data,
                                            const float* __restrict__ q_embed_w,
                                            const float* __restrict__ read_w,
                                            const float* __restrict__ read_b,
                                            const float* __restrict__ pred_w,
                                            const float* __restrict__ pred_b,
                                            const float* __restrict__ target,
                                            float* __restrict__ out,
                                            float* __restrict__ acc) {
    __shared__ float Wl[64 * 196];   // 50.2 KB
    __shared__ float xl[64 * 100];   // 25.6 KB
    int tid = threadIdx.x;
    int r0 = blockIdx.x * 64;
    int fq = tid & 15;
    int rh = tid >> 4;   // 0..15

    for (int i = tid; i < 3072; i += 256) {   // 64 f x 48 float4, once
        int f = i / 48, p = i - f * 48;
        *(float4*)(Wl + f * 196 + p * 4) = *(const float4*)(read_w + f * 192 + p * 4);
    }

    float accv[4][4];
#pragma unroll
    for (int i = 0; i < 4; i++)
#pragma unroll
        for (int j = 0; j < 4; j++) accv[i][j] = 0.f;

    for (int kc = 0; kc < 2; kc++) {
        __syncthreads();
        for (int i = tid; i < 1536; i += 256) {   // 64 rows x 24 float4
            int r = i / 24, p = i - r * 24;
            float4 val;
            if (kc == 0) {
                val = *(const float4*)(Rr + (long)(r0 + r) * DVV + p * 4);
            } else if (p < 8) {
                val = *(const float4*)(Rr + (long)(r0 + r) * DVV + 96 + p * 4);
            } else {
                int qi = q_data[r0 + r];
                val = *(const float4*)(q_embed_w + (long)qi * DKK + (p - 8) * 4);
            }
            *(float4*)(xl + r * 100 + p * 4) = val;
        }
        __syncthreads();
#pragma unroll 4
        for (int kk = 0; kk < 96; kk += 4) {
            float4 wv[4], x4[4];
#pragma unroll
            for (int i = 0; i < 4; i++)
                wv[i] = *(const float4*)(Wl + (fq + 16 * i) * 196 + kc * 96 + kk);
#pragma unroll
            for (int j = 0; j < 4; j++)
                x4[j] = *(const float4*)(xl + (rh * 4 + j) * 100 + kk);
#pragma unroll
            for (int i = 0; i < 4; i++)
#pragma unroll
                for (int j = 0; j < 4; j++) {
                    accv[i][j] = fmaf(x4[j].x, wv[i].x, accv[i][j]);
                    accv[i][j] = fmaf(x4[j].y, wv[i].y, accv[i][j]);
                    accv[i][j] = fmaf(x4[j].z, wv[i].z, accv[i][j]);
                    accv[i][j] = fmaf(x4[j].w, wv[i].w, accv[i][j]);
                }
        }
    }

    float pb = pred_b[0];
    float rb_[4], pw_[4];
#pragma unroll
    for (int i = 0; i < 4; i++) { rb_[i] = read_b[fq + 16 * i]; pw_[i] = pred_w[fq + 16 * i]; }

    float bce_sum = 0.f, cnt = 0.f;
#pragma unroll
    for (int j = 0; j < 4; j++) {
        float pv = 0.f;
#pragma unroll
        for (int i = 0; i < 4; i++)
            pv = fmaf(pw_[i], tanhf(accv[i][j] + rb_[i]), pv);
        pv += __shfl_xor(pv, 1, 64);
        pv += __shfl_xor(pv, 2, 64);
        pv += __shfl_xor(pv, 4, 64);
        pv += __shfl_xor(pv, 8, 64);
        if (fq == 0) {
            int row = r0 + rh * 4 + j;
            float tgt = target[row];
            float logit = pv + pb;
            float prob = 0.f;
            if (tgt >= 0.f) {
                prob = 1.f / (1.f + expf(-logit));
                float bce = fmaxf(logit, 0.f) - logit * tgt + log1pf(expf(-fabsf(logit)));
                bce_sum += bce;
                cnt += 1.f;
            }
            out[1 + row] = prob;
        }
    }
    if (fq == 0) {
        atomicAdd(&acc[0], bce_sum);
        atomicAdd(&acc[1], cnt);
    }
}

// ---------------- Kernel 5: finalize loss ----------------
__global__ void k_loss(const float* __restrict__ acc, float* __restrict__ out) {
    out[0] = acc[0] / fmaxf(acc[1], 1.f);
}

extern "C" void kernel_launch(void* const* d_in, const int* in_sizes, int n_in,
                              void* d_out, int out_size, void* d_ws, size_t ws_size,
                              hipStream_t stream) {
    const int*   q_data     = (const int*)d_in[0];
    const int*   qa_data    = (const int*)d_in[1];
    const float* target     = (const float*)d_in[2];
    const float* q_embed_w  = (const float*)d_in[3];
    const float* qa_embed_w = (const float*)d_in[4];
    const float* mem_key    = (const float*)d_in[5];
    const float* init_mv    = (const float*)d_in[6];
    const float* erase_w    = (const float*)d_in[7];
    const float* erase_b    = (const float*)d_in[8];
    const float* add_w      = (const float*)d_in[9];
    const float* add_b      = (const float*)d_in[10];
    const float* read_w     = (const float*)d_in[11];
    const float* read_b     = (const float*)d_in[12];
    const float* pred_w     = (const float*)d_in[13];
    const float* pred_b     = (const float*)d_in[14];
    float* out = (float*)d_out;
    float* ws  = (float*)d_ws;

    float* w_all = ws + W_OFF;
    float* E     = ws + E_OFF;
    float* A     = ws + A_OFF;
    float* R     = ws + R_OFF;
    float* acc   = ws + ACC_OFF;

    k_scores<<<NROW / 128, 128, 0, stream>>>(q_data, q_embed_w, mem_key, w_all, acc);
    k_ea<<<NROW / 64, 256, 0, stream>>>(qa_data, qa_embed_w, erase_w, erase_b,
                                        add_w, add_b, E, A);
    k_scan<<<BB * 4, 512, 0, stream>>>(w_all, E, A, init_mv, R);
    k_fc<<<NROW / 64, 256, 0, stream>>>(R, q_data, q_embed_w, read_w, read_b,
                                        pred_w, pred_b, target, out, acc);
    k_loss<<<1, 1, 0, stream>>>(acc, out);
}

// Round 7
// 263.949 us; speedup vs baseline: 1.1680x; 1.1680x over previous
//
#include <hip/hip_runtime.h>
#include <math.h>

#define BB 128
#define SS 200
#define MM 50
#define DKK 64
#define DVV 128
#define FF 64
#define NROW (BB*SS)   // 25600

// w padded layout: direct m index, 64 floats/row, m in [0,50) valid, rest zero
#define WROW 64
#define CCH 8          // scan chunks (= waves per block)
#define CLEN 25        // steps per chunk

// workspace layout (floats)
#define W_OFF   0L
#define EA_OFF  (W_OFF + (long)NROW*WROW)        // interleaved (e,a) float2
#define R_OFF   (EA_OFF + (long)NROW*DVV*2)
#define ACC_OFF (R_OFF + (long)NROW*DVV)

__device__ __forceinline__ float rlane(float v, int l) {
    return __builtin_bit_cast(float, __builtin_amdgcn_readlane(__builtin_bit_cast(unsigned, v), l));
}

// ---------------- Kernel 1: w = softmax(q_e @ mem_key^T) ----------------
__global__ __launch_bounds__(128) void k_scores(const int* __restrict__ q_data,
                                                const float* __restrict__ q_embed_w,
                                                const float* __restrict__ mem_key,
                                                float* __restrict__ w_out,
                                                float* __restrict__ acc) {
    __shared__ float4 mk[MM * 16];   // 12.8 KB
    int tid = threadIdx.x;
    const float4* mkg = (const float4*)mem_key;
    for (int i = tid; i < MM * 16; i += 128) mk[i] = mkg[i];
    if (blockIdx.x == 0 && tid == 0) { acc[0] = 0.f; acc[1] = 0.f; }
    __syncthreads();

    int item = blockIdx.x * 128 + tid;
    int qidx = q_data[item];
    const float4* qg = (const float4*)(q_embed_w + (long)qidx * DKK);
    float4 q[16];
#pragma unroll
    for (int i = 0; i < 16; i++) q[i] = qg[i];

    float s[MM];
    float mx = -1e30f;
#pragma unroll 2
    for (int m = 0; m < MM; m++) {
        float a = 0.f;
#pragma unroll
        for (int k4 = 0; k4 < 16; k4++) {
            float4 mkv = mk[m * 16 + k4];
            float4 qv = q[k4];
            a = fmaf(qv.x, mkv.x, a);
            a = fmaf(qv.y, mkv.y, a);
            a = fmaf(qv.z, mkv.z, a);
            a = fmaf(qv.w, mkv.w, a);
        }
        s[m] = a;
        mx = fmaxf(mx, a);
    }
    float sum = 0.f;
#pragma unroll
    for (int m = 0; m < MM; m++) { s[m] = expf(s[m] - mx); sum += s[m]; }
    float inv = 1.f / sum;

    float* wo = w_out + (long)item * WROW;
#pragma unroll
    for (int m = 0; m < MM; m++) wo[m] = s[m] * inv;
#pragma unroll
    for (int m = MM; m < WROW; m++) wo[m] = 0.f;
}

// ---------------- Kernel 2: e/a GEMM — 64 rows x 128 v, output interleaved float2 ----------------
__global__ __launch_bounds__(256) void k_ea(const int* __restrict__ qa_data,
                                            const float* __restrict__ qa_embed_w,
                                            const float* __restrict__ erase_w,
                                            const float* __restrict__ erase_b,
                                            const float* __restrict__ add_w,
                                            const float* __restrict__ add_b,
                                            float* __restrict__ EA) {
    __shared__ float Wel[128 * 36];
    __shared__ float Wal[128 * 36];
    __shared__ float xl[64 * 36];
    int tid = threadIdx.x;
    int r0 = blockIdx.x * 64;
    int vq = tid & 31;
    int rh = tid >> 5;   // 0..7

    float acc_e[4][8], acc_a[4][8];
#pragma unroll
    for (int i = 0; i < 4; i++)
#pragma unroll
        for (int j = 0; j < 8; j++) { acc_e[i][j] = 0.f; acc_a[i][j] = 0.f; }

    for (int kc = 0; kc < 4; kc++) {
        __syncthreads();
        for (int i = tid; i < 2048; i += 256) {
            int mat = i >> 10;
            int r = (i >> 3) & 127, p = i & 7;
            const float* src = (mat ? add_w : erase_w) + r * 128 + kc * 32 + p * 4;
            float* dst = (mat ? Wal : Wel) + r * 36 + p * 4;
            *(float4*)dst = *(const float4*)src;
        }
        for (int i = tid; i < 512; i += 256) {
            int r = i >> 3, p = i & 7;
            int idx = qa_data[r0 + r];
            *(float4*)(xl + r * 36 + p * 4) =
                *(const float4*)(qa_embed_w + (long)idx * DVV + kc * 32 + p * 4);
        }
        __syncthreads();
#pragma unroll
        for (int kk = 0; kk < 32; kk += 4) {
            float4 we[4], wa[4], x4[8];
#pragma unroll
            for (int i = 0; i < 4; i++) {
                we[i] = *(const float4*)(Wel + (vq + 32 * i) * 36 + kk);
                wa[i] = *(const float4*)(Wal + (vq + 32 * i) * 36 + kk);
            }
#pragma unroll
            for (int j = 0; j < 8; j++)
                x4[j] = *(const float4*)(xl + (rh * 8 + j) * 36 + kk);
#pragma unroll
            for (int i = 0; i < 4; i++)
#pragma unroll
                for (int j = 0; j < 8; j++) {
                    acc_e[i][j] = fmaf(x4[j].x, we[i].x, acc_e[i][j]);
                    acc_e[i][j] = fmaf(x4[j].y, we[i].y, acc_e[i][j]);
                    acc_e[i][j] = fmaf(x4[j].z, we[i].z, acc_e[i][j]);
                    acc_e[i][j] = fmaf(x4[j].w, we[i].w, acc_e[i][j]);
                    acc_a[i][j] = fmaf(x4[j].x, wa[i].x, acc_a[i][j]);
                    acc_a[i][j] = fmaf(x4[j].y, wa[i].y, acc_a[i][j]);
                    acc_a[i][j] = fmaf(x4[j].z, wa[i].z, acc_a[i][j]);
                    acc_a[i][j] = fmaf(x4[j].w, wa[i].w, acc_a[i][j]);
                }
        }
    }
#pragma unroll
    for (int i = 0; i < 4; i++) {
        int v = vq + 32 * i;
        float eb = erase_b[v], ab = add_b[v];
#pragma unroll
        for (int j = 0; j < 8; j++) {
            int row = r0 + rh * 8 + j;
            float2 ea;
            ea.x = 1.f / (1.f + expf(-(acc_e[i][j] + eb)));
            ea.y = tanhf(acc_a[i][j] + ab);
            *(float2*)(EA + ((long)row * DVV + v) * 2) = ea;
        }
    }
}

// ---------------- Kernel 3: chunked affine scan ----------------
// Mv_t = alpha_t*Mv_{t-1} + beta_t with alpha=1-w*e, beta=w*a (affine per (b,m,v)).
// Block = (b, v_half): 8 waves = 8 chunks of 25 steps. Lanes = v; m in-lane (regs).
// Pass1: compose chunk map (A,B). Combine: 7 LDS rounds -> chunk start states.
// Pass2: replay chunk emitting reads. Sequential depth 200 -> 25x2.
__global__ __launch_bounds__(512, 2) void k_scan(const float* __restrict__ w_pad,
                                                 const float* __restrict__ EA,
                                                 const float* __restrict__ init_mv,
                                                 float* __restrict__ R) {
    __shared__ float Sb[MM * 64];      // 12.8 KB boundary state
    int b   = blockIdx.x >> 1;
    int vh  = blockIdx.x & 1;
    int tid = threadIdx.x;
    int lane  = tid & 63;
    int chunk = tid >> 6;              // wave id = chunk
    int v  = vh * 64 + lane;
    int t0 = chunk * CLEN;

    const float* wbase = w_pad + ((long)b * SS + t0) * WROW;
    const float* eab   = EA + (((long)b * SS + t0) * DVV + v) * 2;
    float*       Rb    = R + ((long)b * SS + t0) * DVV + v;

    // ---- pass 1: compose the chunk's affine map per m ----
    float A[MM], Bc[MM];
#pragma unroll
    for (int m = 0; m < MM; m++) { A[m] = 1.f; Bc[m] = 0.f; }

    float  w_cur  = wbase[lane];
    float2 ea_cur = *(const float2*)eab;
#pragma unroll 1
    for (int t = 0; t < CLEN; t++) {
        int tp = (t + 1 < CLEN) ? t + 1 : t;
        float  w_nxt  = wbase[tp * WROW + lane];
        float2 ea_nxt = *(const float2*)(eab + (long)tp * DVV * 2);
        float e = ea_cur.x, a = ea_cur.y;
#pragma unroll
        for (int m = 0; m < MM; m++) {
            float wm = rlane(w_cur, m);
            float alpha = fmaf(-wm, e, 1.f);
            A[m] *= alpha;
            Bc[m] = fmaf(alpha, Bc[m], wm * a);
        }
        w_cur = w_nxt; ea_cur = ea_nxt;
    }

    // ---- combine: sequential over waves through LDS ----
    float Mv[MM];
    if (chunk == 0) {
#pragma unroll
        for (int m = 0; m < MM; m++) Mv[m] = init_mv[m * DVV + v];
#pragma unroll
        for (int m = 0; m < MM; m++) Sb[m * 64 + lane] = fmaf(A[m], Mv[m], Bc[m]);
    }
    __syncthreads();
    for (int c = 1; c < CCH; c++) {
        if (chunk == c) {
#pragma unroll
            for (int m = 0; m < MM; m++) Mv[m] = Sb[m * 64 + lane];
            if (c + 1 < CCH) {
#pragma unroll
                for (int m = 0; m < MM; m++) Sb[m * 64 + lane] = fmaf(A[m], Mv[m], Bc[m]);
            }
        }
        __syncthreads();
    }

    // ---- pass 2: replay chunk, emitting reads (pre-update Mv) ----
    w_cur  = wbase[lane];
    ea_cur = *(const float2*)eab;
#pragma unroll 1
    for (int t = 0; t < CLEN; t++) {
        int tp = (t + 1 < CLEN) ? t + 1 : t;
        float  w_nxt  = wbase[tp * WROW + lane];
        float2 ea_nxt = *(const float2*)(eab + (long)tp * DVV * 2);
        float e = ea_cur.x, a = ea_cur.y;
        float rd0 = 0.f, rd1 = 0.f;
#pragma unroll
        for (int m = 0; m < MM; m += 2) {
            float wm0 = rlane(w_cur, m);
            rd0 = fmaf(wm0, Mv[m], rd0);
            float al0 = fmaf(-wm0, e, 1.f);
            Mv[m] = fmaf(al0, Mv[m], wm0 * a);
            float wm1 = rlane(w_cur, m + 1);
            rd1 = fmaf(wm1, Mv[m + 1], rd1);
            float al1 = fmaf(-wm1, e, 1.f);
            Mv[m + 1] = fmaf(al1, Mv[m + 1], wm1 * a);
        }
        Rb[t * DVV] = rd0 + rd1;
        w_cur = w_nxt; ea_cur = ea_nxt;
    }
}

// ---------------- Kernel 4: FC head + BCE — 64 rows x 64 f per block ----------------
__global__ __launch_bounds__(256) void k_fc(const float* __restrict__ Rr,
                                            const int* __restrict__ q_data,
                                            const float* __restrict__ q_embed_w,
                                            const float* __restrict__ read_w,
                                            const float* __restrict__ read_b,
                                            const float* __restrict__ pred_w,
                                            const float* __restrict__ pred_b,
                                            const float* __restrict__ target,
                                            float* __restrict__ out,
                                            float* __restrict__ acc) {
    __shared__ float Wl[64 * 196];   // 50.2 KB
    __shared__ float xl[64 * 100];   // 25.6 KB
    int tid = threadIdx.x;
    int r0 = blockIdx.x * 64;
    int fq = tid & 15;
    int rh = tid >> 4;   // 0..15

    for (int i = tid; i < 3072; i += 256) {
        int f = i / 48, p = i - f * 48;
        *(float4*)(Wl + f * 196 + p * 4) = *(const float4*)(read_w + f * 192 + p * 4);
    }

    float accv[4][4];
#pragma unroll
    for (int i = 0; i < 4; i++)
#pragma unroll
        for (int j = 0; j < 4; j++) accv[i][j] = 0.f;

    for (int kc = 0; kc < 2; kc++) {
        __syncthreads();
        for (int i = tid; i < 1536; i += 256) {
            int r = i / 24, p = i - r * 24;
            float4 val;
            if (kc == 0) {
                val = *(const float4*)(Rr + (long)(r0 + r) * DVV + p * 4);
            } else if (p < 8) {
                val = *(const float4*)(Rr + (long)(r0 + r) * DVV + 96 + p * 4);
            } else {
                int qi = q_data[r0 + r];
                val = *(const float4*)(q_embed_w + (long)qi * DKK + (p - 8) * 4);
            }
            *(float4*)(xl + r * 100 + p * 4) = val;
        }
        __syncthreads();
#pragma unroll 4
        for (int kk = 0; kk < 96; kk += 4) {
            float4 wv[4], x4[4];
#pragma unroll
            for (int i = 0; i < 4; i++)
                wv[i] = *(const float4*)(Wl + (fq + 16 * i) * 196 + kc * 96 + kk);
#pragma unroll
            for (int j = 0; j < 4; j++)
                x4[j] = *(const float4*)(xl + (rh * 4 + j) * 100 + kk);
#pragma unroll
            for (int i = 0; i < 4; i++)
#pragma unroll
                for (int j = 0; j < 4; j++) {
                    accv[i][j] = fmaf(x4[j].x, wv[i].x, accv[i][j]);
                    accv[i][j] = fmaf(x4[j].y, wv[i].y, accv[i][j]);
                    accv[i][j] = fmaf(x4[j].z, wv[i].z, accv[i][j]);
                    accv[i][j] = fmaf(x4[j].w, wv[i].w, accv[i][j]);
                }
        }
    }

    float pb = pred_b[0];
    float rb_[4], pw_[4];
#pragma unroll
    for (int i = 0; i < 4; i++) { rb_[i] = read_b[fq + 16 * i]; pw_[i] = pred_w[fq + 16 * i]; }

    float bce_sum = 0.f, cnt = 0.f;
#pragma unroll
    for (int j = 0; j < 4; j++) {
        float pv = 0.f;
#pragma unroll
        for (int i = 0; i < 4; i++)
            pv = fmaf(pw_[i], tanhf(accv[i][j] + rb_[i]), pv);
        pv += __shfl_xor(pv, 1, 64);
        pv += __shfl_xor(pv, 2, 64);
        pv += __shfl_xor(pv, 4, 64);
        pv += __shfl_xor(pv, 8, 64);
        if (fq == 0) {
            int row = r0 + rh * 4 + j;
            float tgt = target[row];
            float logit = pv + pb;
            float prob = 0.f;
            if (tgt >= 0.f) {
                prob = 1.f / (1.f + expf(-logit));
                float bce = fmaxf(logit, 0.f) - logit * tgt + log1pf(expf(-fabsf(logit)));
                bce_sum += bce;
                cnt += 1.f;
            }
            out[1 + row] = prob;
        }
    }
    if (fq == 0) {
        atomicAdd(&acc[0], bce_sum);
        atomicAdd(&acc[1], cnt);
    }
}

// ---------------- Kernel 5: finalize loss ----------------
__global__ void k_loss(const float* __restrict__ acc, float* __restrict__ out) {
    out[0] = acc[0] / fmaxf(acc[1], 1.f);
}

extern "C" void kernel_launch(void* const* d_in, const int* in_sizes, int n_in,
                              void* d_out, int out_size, void* d_ws, size_t ws_size,
                              hipStream_t stream) {
    const int*   q_data     = (const int*)d_in[0];
    const int*   qa_data    = (const int*)d_in[1];
    const float* target     = (const float*)d_in[2];
    const float* q_embed_w  = (const float*)d_in[3];
    const float* qa_embed_w = (const float*)d_in[4];
    const float* mem_key    = (const float*)d_in[5];
    const float* init_mv    = (const float*)d_in[6];
    const float* erase_w    = (const float*)d_in[7];
    const float* erase_b    = (const float*)d_in[8];
    const float* add_w      = (const float*)d_in[9];
    const float* add_b      = (const float*)d_in[10];
    const float* read_w     = (const float*)d_in[11];
    const float* read_b     = (const float*)d_in[12];
    const float* pred_w     = (const float*)d_in[13];
    const float* pred_b     = (const float*)d_in[14];
    float* out = (float*)d_out;
    float* ws  = (float*)d_ws;

    float* w_all = ws + W_OFF;
    float* EA    = ws + EA_OFF;
    float* R     = ws + R_OFF;
    float* acc   = ws + ACC_OFF;

    k_scores<<<NROW / 128, 128, 0, stream>>>(q_data, q_embed_w, mem_key, w_all, acc);
    k_ea<<<NROW / 64, 256, 0, stream>>>(qa_data, qa_embed_w, erase_w, erase_b,
                                        add_w, add_b, EA);
    k_scan<<<BB * 2, 512, 0, stream>>>(w_all, EA, init_mv, R);
    k_fc<<<NROW / 64, 256, 0, stream>>>(R, q_data, q_embed_w, read_w, read_b,
                                        pred_w, pred_b, target, out, acc);
    k_loss<<<1, 1, 0, stream>>>(acc, out);
}

// Round 8
// 228.071 us; speedup vs baseline: 1.3518x; 1.1573x over previous
//
#include <hip/hip_runtime.h>
#include <math.h>

#define BB 128
#define SS 200
#define MM 50
#define DKK 64
#define DVV 128
#define FF 64
#define NROW (BB*SS)   // 25600

// w padded layout: direct m index, 64 floats/row, m in [0,50) valid, rest zero
#define WROW 64
#define CCH 8          // scan chunks (= waves per block)
#define CLEN 25        // steps per chunk
#define NFCB (NROW/64) // 400 k_fc blocks

// workspace layout (floats)
#define W_OFF   0L
#define EA_OFF  (W_OFF + (long)NROW*WROW)        // interleaved (e,a) float2
#define R_OFF   (EA_OFF + (long)NROW*DVV*2)
#define ACC_OFF (R_OFF + (long)NROW*DVV)         // NFCB float2 partials

__device__ __forceinline__ float rlane(float v, int l) {
    return __builtin_bit_cast(float, __builtin_amdgcn_readlane(__builtin_bit_cast(unsigned, v), l));
}

// ---------------- Kernel 1: w = softmax(q_e @ mem_key^T) ----------------
__global__ __launch_bounds__(128) void k_scores(const int* __restrict__ q_data,
                                                const float* __restrict__ q_embed_w,
                                                const float* __restrict__ mem_key,
                                                float* __restrict__ w_out) {
    __shared__ float4 mk[MM * 16];   // 12.8 KB
    int tid = threadIdx.x;
    const float4* mkg = (const float4*)mem_key;
    for (int i = tid; i < MM * 16; i += 128) mk[i] = mkg[i];
    __syncthreads();

    int item = blockIdx.x * 128 + tid;
    int qidx = q_data[item];
    const float4* qg = (const float4*)(q_embed_w + (long)qidx * DKK);
    float4 q[16];
#pragma unroll
    for (int i = 0; i < 16; i++) q[i] = qg[i];

    float s[MM];
    float mx = -1e30f;
#pragma unroll 2
    for (int m = 0; m < MM; m++) {
        float a = 0.f;
#pragma unroll
        for (int k4 = 0; k4 < 16; k4++) {
            float4 mkv = mk[m * 16 + k4];
            float4 qv = q[k4];
            a = fmaf(qv.x, mkv.x, a);
            a = fmaf(qv.y, mkv.y, a);
            a = fmaf(qv.z, mkv.z, a);
            a = fmaf(qv.w, mkv.w, a);
        }
        s[m] = a;
        mx = fmaxf(mx, a);
    }
    float sum = 0.f;
#pragma unroll
    for (int m = 0; m < MM; m++) { s[m] = expf(s[m] - mx); sum += s[m]; }
    float inv = 1.f / sum;

    float* wo = w_out + (long)item * WROW;
#pragma unroll
    for (int m = 0; m < MM; m++) wo[m] = s[m] * inv;
#pragma unroll
    for (int m = MM; m < WROW; m++) wo[m] = 0.f;
}

// ---------------- Kernel 2: e/a GEMM — 64 rows x 128 v, output interleaved float2 ----------------
__global__ __launch_bounds__(256) void k_ea(const int* __restrict__ qa_data,
                                            const float* __restrict__ qa_embed_w,
                                            const float* __restrict__ erase_w,
                                            const float* __restrict__ erase_b,
                                            const float* __restrict__ add_w,
                                            const float* __restrict__ add_b,
                                            float* __restrict__ EA) {
    __shared__ float Wel[128 * 36];
    __shared__ float Wal[128 * 36];
    __shared__ float xl[64 * 36];
    int tid = threadIdx.x;
    int r0 = blockIdx.x * 64;
    int vq = tid & 31;
    int rh = tid >> 5;   // 0..7

    float acc_e[4][8], acc_a[4][8];
#pragma unroll
    for (int i = 0; i < 4; i++)
#pragma unroll
        for (int j = 0; j < 8; j++) { acc_e[i][j] = 0.f; acc_a[i][j] = 0.f; }

    for (int kc = 0; kc < 4; kc++) {
        __syncthreads();
        for (int i = tid; i < 2048; i += 256) {
            int mat = i >> 10;
            int r = (i >> 3) & 127, p = i & 7;
            const float* src = (mat ? add_w : erase_w) + r * 128 + kc * 32 + p * 4;
            float* dst = (mat ? Wal : Wel) + r * 36 + p * 4;
            *(float4*)dst = *(const float4*)src;
        }
        for (int i = tid; i < 512; i += 256) {
            int r = i >> 3, p = i & 7;
            int idx = qa_data[r0 + r];
            *(float4*)(xl + r * 36 + p * 4) =
                *(const float4*)(qa_embed_w + (long)idx * DVV + kc * 32 + p * 4);
        }
        __syncthreads();
#pragma unroll
        for (int kk = 0; kk < 32; kk += 4) {
            float4 we[4], wa[4], x4[8];
#pragma unroll
            for (int i = 0; i < 4; i++) {
                we[i] = *(const float4*)(Wel + (vq + 32 * i) * 36 + kk);
                wa[i] = *(const float4*)(Wal + (vq + 32 * i) * 36 + kk);
            }
#pragma unroll
            for (int j = 0; j < 8; j++)
                x4[j] = *(const float4*)(xl + (rh * 8 + j) * 36 + kk);
#pragma unroll
            for (int i = 0; i < 4; i++)
#pragma unroll
                for (int j = 0; j < 8; j++) {
                    acc_e[i][j] = fmaf(x4[j].x, we[i].x, acc_e[i][j]);
                    acc_e[i][j] = fmaf(x4[j].y, we[i].y, acc_e[i][j]);
                    acc_e[i][j] = fmaf(x4[j].z, we[i].z, acc_e[i][j]);
                    acc_e[i][j] = fmaf(x4[j].w, we[i].w, acc_e[i][j]);
                    acc_a[i][j] = fmaf(x4[j].x, wa[i].x, acc_a[i][j]);
                    acc_a[i][j] = fmaf(x4[j].y, wa[i].y, acc_a[i][j]);
                    acc_a[i][j] = fmaf(x4[j].z, wa[i].z, acc_a[i][j]);
                    acc_a[i][j] = fmaf(x4[j].w, wa[i].w, acc_a[i][j]);
                }
        }
    }
#pragma unroll
    for (int i = 0; i < 4; i++) {
        int v = vq + 32 * i;
        float eb = erase_b[v], ab = add_b[v];
#pragma unroll
        for (int j = 0; j < 8; j++) {
            int row = r0 + rh * 8 + j;
            float2 ea;
            ea.x = 1.f / (1.f + expf(-(acc_e[i][j] + eb)));
            ea.y = tanhf(acc_a[i][j] + ab);
            *(float2*)(EA + ((long)row * DVV + v) * 2) = ea;
        }
    }
}

// ---------------- Kernel 3: chunked affine scan ----------------
__global__ __launch_bounds__(512, 2) void k_scan(const float* __restrict__ w_pad,
                                                 const float* __restrict__ EA,
                                                 const float* __restrict__ init_mv,
                                                 float* __restrict__ R) {
    __shared__ float Sb[MM * 64];      // 12.8 KB boundary state
    int b   = blockIdx.x >> 1;
    int vh  = blockIdx.x & 1;
    int tid = threadIdx.x;
    int lane  = tid & 63;
    int chunk = tid >> 6;              // wave id = chunk
    int v  = vh * 64 + lane;
    int t0 = chunk * CLEN;

    const float* wbase = w_pad + ((long)b * SS + t0) * WROW;
    const float* eab   = EA + (((long)b * SS + t0) * DVV + v) * 2;
    float*       Rb    = R + ((long)b * SS + t0) * DVV + v;

    // ---- pass 1: compose the chunk's affine map per m ----
    float A[MM], Bc[MM];
#pragma unroll
    for (int m = 0; m < MM; m++) { A[m] = 1.f; Bc[m] = 0.f; }

    float  w_cur  = wbase[lane];
    float2 ea_cur = *(const float2*)eab;
#pragma unroll 1
    for (int t = 0; t < CLEN; t++) {
        int tp = (t + 1 < CLEN) ? t + 1 : t;
        float  w_nxt  = wbase[tp * WROW + lane];
        float2 ea_nxt = *(const float2*)(eab + (long)tp * DVV * 2);
        float e = ea_cur.x, a = ea_cur.y;
#pragma unroll
        for (int m = 0; m < MM; m++) {
            float wm = rlane(w_cur, m);
            float alpha = fmaf(-wm, e, 1.f);
            A[m] *= alpha;
            Bc[m] = fmaf(alpha, Bc[m], wm * a);
        }
        w_cur = w_nxt; ea_cur = ea_nxt;
    }

    // ---- combine: sequential over waves through LDS ----
    float Mv[MM];
    if (chunk == 0) {
#pragma unroll
        for (int m = 0; m < MM; m++) Mv[m] = init_mv[m * DVV + v];
#pragma unroll
        for (int m = 0; m < MM; m++) Sb[m * 64 + lane] = fmaf(A[m], Mv[m], Bc[m]);
    }
    __syncthreads();
    for (int c = 1; c < CCH; c++) {
        if (chunk == c) {
#pragma unroll
            for (int m = 0; m < MM; m++) Mv[m] = Sb[m * 64 + lane];
            if (c + 1 < CCH) {
#pragma unroll
                for (int m = 0; m < MM; m++) Sb[m * 64 + lane] = fmaf(A[m], Mv[m], Bc[m]);
            }
        }
        __syncthreads();
    }

    // ---- pass 2: replay chunk, emitting reads (pre-update Mv) ----
    w_cur  = wbase[lane];
    ea_cur = *(const float2*)eab;
#pragma unroll 1
    for (int t = 0; t < CLEN; t++) {
        int tp = (t + 1 < CLEN) ? t + 1 : t;
        float  w_nxt  = wbase[tp * WROW + lane];
        float2 ea_nxt = *(const float2*)(eab + (long)tp * DVV * 2);
        float e = ea_cur.x, a = ea_cur.y;
        float rd0 = 0.f, rd1 = 0.f;
#pragma unroll
        for (int m = 0; m < MM; m += 2) {
            float wm0 = rlane(w_cur, m);
            rd0 = fmaf(wm0, Mv[m], rd0);
            float al0 = fmaf(-wm0, e, 1.f);
            Mv[m] = fmaf(al0, Mv[m], wm0 * a);
            float wm1 = rlane(w_cur, m + 1);
            rd1 = fmaf(wm1, Mv[m + 1], rd1);
            float al1 = fmaf(-wm1, e, 1.f);
            Mv[m + 1] = fmaf(al1, Mv[m + 1], wm1 * a);
        }
        Rb[t * DVV] = rd0 + rd1;
        w_cur = w_nxt; ea_cur = ea_nxt;
    }
}

// ---------------- Kernel 4: FC head + BCE — NO global atomics ----------------
// Per-block (bce,cnt) partial written to part[blockIdx]; k_loss reduces.
__global__ __launch_bounds__(256) void k_fc(const float* __restrict__ Rr,
                                            const int* __restrict__ q_data,
                                            const float* __restrict__ q_embed_w,
                                            const float* __restrict__ read_w,
                                            const float* __restrict__ read_b,
                                            const float* __restrict__ pred_w,
                                            const float* __restrict__ pred_b,
                                            const float* __restrict__ target,
                                            float* __restrict__ out,
                                            float2* __restrict__ part) {
    __shared__ float Wl[64 * 196];   // 50.2 KB
    __shared__ float xl[64 * 100];   // 25.6 KB
    __shared__ float2 red[4];
    int tid = threadIdx.x;
    int r0 = blockIdx.x * 64;
    int fq = tid & 15;
    int rh = tid >> 4;   // 0..15

    for (int i = tid; i < 3072; i += 256) {
        int f = i / 48, p = i - f * 48;
        *(float4*)(Wl + f * 196 + p * 4) = *(const float4*)(read_w + f * 192 + p * 4);
    }

    float accv[4][4];
#pragma unroll
    for (int i = 0; i < 4; i++)
#pragma unroll
        for (int j = 0; j < 4; j++) accv[i][j] = 0.f;

    for (int kc = 0; kc < 2; kc++) {
        __syncthreads();
        for (int i = tid; i < 1536; i += 256) {
            int r = i / 24, p = i - r * 24;
            float4 val;
            if (kc == 0) {
                val = *(const float4*)(Rr + (long)(r0 + r) * DVV + p * 4);
            } else if (p < 8) {
                val = *(const float4*)(Rr + (long)(r0 + r) * DVV + 96 + p * 4);
            } else {
                int qi = q_data[r0 + r];
                val = *(const float4*)(q_embed_w + (long)qi * DKK + (p - 8) * 4);
            }
            *(float4*)(xl + r * 100 + p * 4) = val;
        }
        __syncthreads();
#pragma unroll 4
        for (int kk = 0; kk < 96; kk += 4) {
            float4 wv[4], x4[4];
#pragma unroll
            for (int i = 0; i < 4; i++)
                wv[i] = *(const float4*)(Wl + (fq + 16 * i) * 196 + kc * 96 + kk);
#pragma unroll
            for (int j = 0; j < 4; j++)
                x4[j] = *(const float4*)(xl + (rh * 4 + j) * 100 + kk);
#pragma unroll
            for (int i = 0; i < 4; i++)
#pragma unroll
                for (int j = 0; j < 4; j++) {
                    accv[i][j] = fmaf(x4[j].x, wv[i].x, accv[i][j]);
                    accv[i][j] = fmaf(x4[j].y, wv[i].y, accv[i][j]);
                    accv[i][j] = fmaf(x4[j].z, wv[i].z, accv[i][j]);
                    accv[i][j] = fmaf(x4[j].w, wv[i].w, accv[i][j]);
                }
        }
    }

    float pb = pred_b[0];
    float rb_[4], pw_[4];
#pragma unroll
    for (int i = 0; i < 4; i++) { rb_[i] = read_b[fq + 16 * i]; pw_[i] = pred_w[fq + 16 * i]; }

    float bce_sum = 0.f, cnt = 0.f;
#pragma unroll
    for (int j = 0; j < 4; j++) {
        float pv = 0.f;
#pragma unroll
        for (int i = 0; i < 4; i++)
            pv = fmaf(pw_[i], tanhf(accv[i][j] + rb_[i]), pv);
        pv += __shfl_xor(pv, 1, 64);
        pv += __shfl_xor(pv, 2, 64);
        pv += __shfl_xor(pv, 4, 64);
        pv += __shfl_xor(pv, 8, 64);
        if (fq == 0) {
            int row = r0 + rh * 4 + j;
            float tgt = target[row];
            float logit = pv + pb;
            float prob = 0.f;
            if (tgt >= 0.f) {
                prob = 1.f / (1.f + expf(-logit));
                float bce = fmaxf(logit, 0.f) - logit * tgt + log1pf(expf(-fabsf(logit)));
                bce_sum += bce;
                cnt += 1.f;
            }
            out[1 + row] = prob;
        }
    }
    // block reduction: values live on lanes with fq==0 (4 lanes/wave)
    bce_sum += __shfl_xor(bce_sum, 16, 64);
    bce_sum += __shfl_xor(bce_sum, 32, 64);
    cnt     += __shfl_xor(cnt, 16, 64);
    cnt     += __shfl_xor(cnt, 32, 64);
    int lane = tid & 63, wid = tid >> 6;
    if (lane == 0) { red[wid].x = bce_sum; red[wid].y = cnt; }
    __syncthreads();
    if (tid == 0) {
        float2 p;
        p.x = red[0].x + red[1].x + red[2].x + red[3].x;
        p.y = red[0].y + red[1].y + red[2].y + red[3].y;
        part[blockIdx.x] = p;
    }
}

// ---------------- Kernel 5: reduce partials -> loss ----------------
__global__ __launch_bounds__(256) void k_loss(const float2* __restrict__ part,
                                              float* __restrict__ out) {
    __shared__ float2 red[4];
    int tid = threadIdx.x;
    float b = 0.f, c = 0.f;
    for (int i = tid; i < NFCB; i += 256) {
        float2 p = part[i];
        b += p.x; c += p.y;
    }
#pragma unroll
    for (int off = 32; off; off >>= 1) {
        b += __shfl_xor(b, off, 64);
        c += __shfl_xor(c, off, 64);
    }
    int lane = tid & 63, wid = tid >> 6;
    if (lane == 0) { red[wid].x = b; red[wid].y = c; }
    __syncthreads();
    if (tid == 0) {
        float B = red[0].x + red[1].x + red[2].x + red[3].x;
        float C = red[0].y + red[1].y + red[2].y + red[3].y;
        out[0] = B / fmaxf(C, 1.f);
    }
}

extern "C" void kernel_launch(void* const* d_in, const int* in_sizes, int n_in,
                              void* d_out, int out_size, void* d_ws, size_t ws_size,
                              hipStream_t stream) {
    const int*   q_data     = (const int*)d_in[0];
    const int*   qa_data    = (const int*)d_in[1];
    const float* target     = (const float*)d_in[2];
    const float* q_embed_w  = (const float*)d_in[3];
    const float* qa_embed_w = (const float*)d_in[4];
    const float* mem_key    = (const float*)d_in[5];
    const float* init_mv    = (const float*)d_in[6];
    const float* erase_w    = (const float*)d_in[7];
    const float* erase_b    = (const float*)d_in[8];
    const float* add_w      = (const float*)d_in[9];
    const float* add_b      = (const float*)d_in[10];
    const float* read_w     = (const float*)d_in[11];
    const float* read_b     = (const float*)d_in[12];
    const float* pred_w     = (const float*)d_in[13];
    const float* pred_b     = (const float*)d_in[14];
    float* out = (float*)d_out;
    float* ws  = (float*)d_ws;

    float*  w_all = ws + W_OFF;
    float*  EA    = ws + EA_OFF;
    float*  R     = ws + R_OFF;
    float2* part  = (float2*)(ws + ACC_OFF);

    k_scores<<<NROW / 128, 128, 0, stream>>>(q_data, q_embed_w, mem_key, w_all);
    k_ea<<<NROW / 64, 256, 0, stream>>>(qa_data, qa_embed_w, erase_w, erase_b,
                                        add_w, add_b, EA);
    k_scan<<<BB * 2, 512, 0, stream>>>(w_all, EA, init_mv, R);
    k_fc<<<NFCB, 256, 0, stream>>>(R, q_data, q_embed_w, read_w, read_b,
                                   pred_w, pred_b, target, out, part);
    k_loss<<<1, 256, 0, stream>>>(part, out);
}